// Round 18
// baseline (42716.452 us; speedup 1.0000x reference)
//
#include <hip/hip_runtime.h>
#include <math.h>

#define FD 128
#define HD 512
#define TFS 16
#define NSTEP 255
#define TOTAL 256
#define NWG 256
#define THREADS 1024

// ws dword offsets
#define WS_FLAG 0                         // 2 chains x 256 flags (padded to 512 each)
#define WS_H0   1024                      // [dir][buf][256 kp][64 b][2] fp32 pair-k
#define WS_H1   (WS_H0 + 131072)
#define WS_XIN  (WS_H1 + 131072)          // [dir][16 s][64 fp][64 b][2] fp32 pair-k
#define WS_M    (WS_XIN + 262144)         // [2048 r][512 j] fused Wih0@outW
#define WS_END  (WS_M + 1048576)
#define WS_ZERO WS_XIN                    // zero flags + H0 + H1

__device__ __forceinline__ float sigm(float v) { return 1.0f / (1.0f + __expf(-v)); }

// STORES: agent-scope write-through (visible at LLC after vmcnt0; never dirty L1/L2).
// READS : plain cached loads (L1/L2 amplify the 256-wg broadcast); coherence is
//         restored by a bulk acquire-invalidate in bar_wait after every flag sync.
__device__ __forceinline__ float ldf(const float* p) { return *p; }
__device__ __forceinline__ float2 ldf2(const float* p) { return *(const float2*)p; }
__device__ __forceinline__ void astf(float* p, float v) {
    __hip_atomic_store(p, v, __ATOMIC_RELAXED, __HIP_MEMORY_SCOPE_AGENT);
}
__device__ __forceinline__ unsigned aldu(const unsigned* p) {
    return __hip_atomic_load(p, __ATOMIC_RELAXED, __HIP_MEMORY_SCOPE_AGENT);
}

// arrival: every wave drains its own write-through stores, then barrier, then flag store
__device__ __forceinline__ void bar_arrive(unsigned* flags, int wid, unsigned val) {
    asm volatile("s_waitcnt vmcnt(0)" ::: "memory");
    __syncthreads();
    if (threadIdx.x == 0) {
        __hip_atomic_store(flags + wid, val, __ATOMIC_RELAXED, __HIP_MEMORY_SCOPE_AGENT);
    }
}
// wait: wave0 polls all 256 flags, then ALL threads acquire-invalidate L1/L2 so
// subsequent plain loads refill fresh from LLC.
__device__ __forceinline__ void bar_wait(const unsigned* flags, unsigned val) {
    if (threadIdx.x < 64) {
        const int l = threadIdx.x;
        for (;;) {
            unsigned m0 = aldu(flags + l);
            unsigned m1 = aldu(flags + l + 64);
            unsigned m2 = aldu(flags + l + 128);
            unsigned m3 = aldu(flags + l + 192);
            unsigned a = m0 < m1 ? m0 : m1;
            unsigned b = m2 < m3 ? m2 : m3;
            unsigned mn = a < b ? a : b;
            if (__all(mn >= val)) break;
            __builtin_amdgcn_s_sleep(1);
        }
    }
    __syncthreads();
    __builtin_amdgcn_fence(__ATOMIC_ACQUIRE, "agent");
}

// a1[8] (+ a2[8] if DUAL) += W(8 rows x NCH*8 k, LDS broadcast) @ act(k x 64, lane=col)
// Pair-k act layout: element (k,b) at (k>>1)*128 + 2b + (k&1); caller passes
// act = base + (kbase>>1)*128 + 2*lane. Chunk stride = 512 floats.
// Acts via plain cached 8B loads (L2-served broadcast).
template<int NCH, bool DUAL>
__device__ __forceinline__ void gemv8(const float* __restrict__ act,
                                      const float* __restrict__ w1, int s1,
                                      const float* __restrict__ w2, int s2,
                                      float* __restrict__ a1, float* __restrict__ a2)
{
    float2 ab[2][4];
#pragma unroll
    for (int p = 0; p < 4; ++p) ab[0][p] = ldf2(act + p * 128);
#pragma unroll
    for (int c = 0; c < NCH; ++c) {
        if (c + 1 < NCH) {
            const float* an = act + (c + 1) * 512;
#pragma unroll
            for (int p = 0; p < 4; ++p) ab[(c + 1) & 1][p] = ldf2(an + p * 128);
        }
        const float2* cb = ab[c & 1];
#pragma unroll
        for (int r = 0; r < 8; ++r) {
            const float* wr = w1 + r * s1 + c * 8;
            const float4 u0 = *(const float4*)wr;
            const float4 u1 = *(const float4*)(wr + 4);
            a1[r] = fmaf(u0.x, cb[0].x, a1[r]); a1[r] = fmaf(u0.y, cb[0].y, a1[r]);
            a1[r] = fmaf(u0.z, cb[1].x, a1[r]); a1[r] = fmaf(u0.w, cb[1].y, a1[r]);
            a1[r] = fmaf(u1.x, cb[2].x, a1[r]); a1[r] = fmaf(u1.y, cb[2].y, a1[r]);
            a1[r] = fmaf(u1.w, cb[3].y, fmaf(u1.z, cb[3].x, a1[r]));
        }
        if (DUAL) {
#pragma unroll
            for (int r = 0; r < 8; ++r) {
                const float* wr = w2 + r * s2 + c * 8;
                const float4 u0 = *(const float4*)wr;
                const float4 u1 = *(const float4*)(wr + 4);
                a2[r] = fmaf(u0.x, cb[0].x, a2[r]); a2[r] = fmaf(u0.y, cb[0].y, a2[r]);
                a2[r] = fmaf(u0.z, cb[1].x, a2[r]); a2[r] = fmaf(u0.w, cb[1].y, a2[r]);
                a2[r] = fmaf(u1.x, cb[2].x, a2[r]); a2[r] = fmaf(u1.y, cb[2].y, a2[r]);
                a2[r] = fmaf(u1.w, cb[3].y, fmaf(u1.z, cb[3].x, a2[r]));
            }
        }
    }
}

// M = Wih0 [2048x128] @ outW [128x512]
__global__ __launch_bounds__(512)
void build_m_kernel(const float* __restrict__ Wih0, const float* __restrict__ outW,
                    float* __restrict__ ws)
{
    __shared__ float wl[16 * 128];
    const int tid = threadIdx.x;
    const int rb = (int)blockIdx.x;
    for (int d = tid; d < 16 * 128; d += 512)
        wl[d] = Wih0[(size_t)(rb * 16 + (d >> 7)) * 128 + (d & 127)];
    __syncthreads();
    const int j = tid;
    float acc[16];
#pragma unroll
    for (int r = 0; r < 16; ++r) acc[r] = 0.f;
    for (int f = 0; f < 128; ++f) {
        const float ov = outW[(size_t)f * 512 + j];
#pragma unroll
        for (int r = 0; r < 16; ++r) acc[r] = fmaf(wl[r * 128 + f], ov, acc[r]);
    }
    float* M = ws + WS_M;
#pragma unroll
    for (int r = 0; r < 16; ++r) M[(size_t)(rb * 16 + r) * 512 + j] = acc[r];
}

// output emission for step s, dir D (weight-0 terms at s=255 dropped by loop bound)
#define EMIT(D) do {                                                                 \
    if (projDir == D && tid < 64) {                                                  \
        float P = outBias;                                                           \
        _Pragma("unroll") for (int w2 = 0; w2 < 16; ++w2) P += projP[w2 * 64 + tid]; \
        float xprev = (s - 1 < TFS)                                                  \
            ? ldf(XinA + (D)*131072 + (s - 1) * 8192 + (fC >> 1) * 128 + tid * 2 + (fC & 1)) \
            : xreg;                                                                  \
        float xn = xprev + P;                                                        \
        xreg = xn;                                                                   \
        int oidx = (D) ? (255 - s) : s;                                              \
        float wgt = (float)(255 - s) * (1.0f / 255.0f);                              \
        atomicAdd(out + ((size_t)tid * TOTAL + oidx) * FD + fC, wgt * xn * sgC);     \
    }                                                                                \
} while (0)

#define A_REGION(D) do {                                                               \
    if (s >= 1 && projDir == D) {                                                      \
        const float* hp = h1r_##D + (wv * 32) * 64 + 2 * l;                            \
        float p = 0.f;                                                                 \
        _Pragma("unroll")                                                              \
        for (int kp = 0; kp < 16; ++kp) {                                              \
            float2 hv = ldf2(hp + kp * 128);                                           \
            p = fmaf(wProj[wv * 32 + 2 * kp], hv.x, p);                                \
            p = fmaf(wProj[wv * 32 + 2 * kp + 1], hv.y, p);                            \
        }                                                                              \
        projP[wv * 64 + l] = p;                                                        \
    }                                                                                  \
    if (!last) {                                                                       \
        float a1[8];                                                                   \
        _Pragma("unroll") for (int r = 0; r < 8; ++r) a1[r] = 0.f;                     \
        if (s < TFS) {                                                                 \
            if (wv < 8) gemv8<2, false>(XinA + (D)*131072 + s * 8192 + (wv * 16) * 64 + 2 * l, \
                                        wWih0 + wv * 16, 128, wWih0, 0, a1, a1);       \
            else        gemv8<8, false>(h0r_##D + ((wv - 8) * 64) * 64 + 2 * l,        \
                                        wWhh0 + (wv - 8) * 64, 512, wWhh0, 0, a1, a1); \
        } else {                                                                       \
            if (wv < 8) {                                                              \
                _Pragma("unroll") for (int r = 0; r < 8; ++r) acc2_##D[r] = 0.f;       \
                gemv8<8, true>(h1r_##D + (wv * 64) * 64 + 2 * l, wM + wv * 64, 512,    \
                               wL1 + 512 + wv * 64, 1024, a1, acc2_##D);               \
            } else                                                                     \
                gemv8<8, false>(h0r_##D + ((wv - 8) * 64) * 64 + 2 * l,                \
                                wWhh0 + (wv - 8) * 64, 512, wWhh0, 0, a1, a1);         \
        }                                                                              \
        _Pragma("unroll") for (int r = 0; r < 8; ++r) pLDS[wv * 512 + r * 64 + l] = a1[r]; \
    }                                                                                  \
    __syncthreads();                                                                   \
    if (!last) {                                                                       \
        if (tid < 128) {                                                               \
            float g[4];                                                                 \
            _Pragma("unroll") for (int gg = 0; gg < 4; ++gg) {                         \
                int rl = gg * 2 + uE;                                                  \
                float ft = 0.f, fh = 0.f;                                              \
                _Pragma("unroll") for (int w2 = 0; w2 < 8; ++w2)  ft += pLDS[w2 * 512 + rl * 64 + bE]; \
                _Pragma("unroll") for (int w2 = 8; w2 < 16; ++w2) fh += pLDS[w2 * 512 + rl * 64 + bE]; \
                if (s < TFS) GA##D[gg] = ft;                                           \
                else         GA##D[gg] += ft + cvec[gg];                               \
                g[gg] = GA##D[gg] + fh + bA[gg];                                       \
            }                                                                          \
            float cn = sigm(g[1]) * cc0_##D + sigm(g[0]) * tanhf(g[2]);                \
            cc0_##D = cn;                                                              \
            astf(h0w_##D + wid * 128 + bE * 2 + uE, sigm(g[3]) * tanhf(cn));           \
        }                                                                              \
        bar_arrive(flags##D, wid, 2u * s + 2u);                                        \
    }                                                                                  \
} while (0)

#define B_REGION(D) do {                                                               \
    bar_wait(flags##D, 2u * s + 2u);                                                   \
    if (s >= 1) EMIT(D);                                                               \
    {                                                                                  \
        float a1[8];                                                                   \
        _Pragma("unroll") for (int r = 0; r < 8; ++r) a1[r] = 0.f;                     \
        if (s < TFS) {                                                                 \
            if (wv < 8) gemv8<8, false>(h0w_##D + (wv * 64) * 64 + 2 * l,              \
                                        wL1 + wv * 64, 1024, wL1, 0, a1, a1);          \
            else        gemv8<8, false>(h1r_##D + ((wv - 8) * 64) * 64 + 2 * l,        \
                                        wL1 + 512 + (wv - 8) * 64, 1024, wL1, 0, a1, a1); \
        } else {                                                                       \
            gemv8<4, false>(h0w_##D + (wv * 32) * 64 + 2 * l, wL1 + wv * 32, 1024, wL1, 0, a1, a1); \
            if (wv < 8) { _Pragma("unroll") for (int r = 0; r < 8; ++r) a1[r] += acc2_##D[r]; } \
        }                                                                              \
        _Pragma("unroll") for (int r = 0; r < 8; ++r) pLDS[wv * 512 + r * 64 + l] = a1[r]; \
    }                                                                                  \
    __syncthreads();                                                                   \
    if (tid < 128) {                                                                   \
        float g[4];                                                                     \
        _Pragma("unroll") for (int gg = 0; gg < 4; ++gg) {                             \
            int rl = gg * 2 + uE;                                                      \
            float fs = 0.f;                                                            \
            _Pragma("unroll") for (int w2 = 0; w2 < 16; ++w2) fs += pLDS[w2 * 512 + rl * 64 + bE]; \
            g[gg] = fs + bB[gg];                                                       \
        }                                                                              \
        float cn = sigm(g[1]) * cc1_##D + sigm(g[0]) * tanhf(g[2]);                    \
        cc1_##D = cn;                                                                  \
        astf(h1w_##D + wid * 128 + bE * 2 + uE, sigm(g[3]) * tanhf(cn));               \
    }                                                                                  \
    bar_arrive(flags##D, wid, 2u * s + 3u);                                            \
} while (0)

__global__ __launch_bounds__(THREADS)
void md_lstm_kernel(const float* __restrict__ x,
                    const float* __restrict__ Wih0, const float* __restrict__ Whh0,
                    const float* __restrict__ bih0, const float* __restrict__ bhh0,
                    const float* __restrict__ Wih1, const float* __restrict__ Whh1,
                    const float* __restrict__ bih1, const float* __restrict__ bhh1,
                    const float* __restrict__ outW, const float* __restrict__ outB,
                    float* __restrict__ out, float* __restrict__ ws)
{
    __shared__ __align__(16) float wWih0[8 * 128];   //  4 KB
    __shared__ __align__(16) float wWhh0[8 * 512];   // 16 KB
    __shared__ __align__(16) float wM[8 * 512];      // 16 KB
    __shared__ __align__(16) float wL1[8 * 1024];    // 32 KB [Wih1|Whh1]
    __shared__ __align__(16) float wProj[512];       //  2 KB
    __shared__ __align__(16) float pLDS[16 * 512];   // 32 KB [wave][8 rl][64 b]
    __shared__ __align__(16) float projP[16 * 64];   //  4 KB
    __shared__ float outBl[128];

    const int tid = threadIdx.x;
    const int bid = (int)blockIdx.x;
    const int wid = bid;                  // wg owns units {2wid, 2wid+1} in both layers/dirs
    const int wv = tid >> 6, l = tid & 63;
    const int projDir = wid & 1;
    const int fC = wid >> 1;

    unsigned* flags0 = (unsigned*)ws + WS_FLAG;
    unsigned* flags1 = flags0 + 512;
    float* XinA = ws + WS_XIN;
    const float* Mg = ws + WS_M;

    // ---------- prologue: transposed signed Xin per dir (pair-k, agent stores) + endpoints
    {
        int q = bid * THREADS + tid;      // exactly 2*16*128*64 = 262144
        int b = q & 63, f = (q >> 6) & 127, s0 = (q >> 13) & 15, dq = (q >> 17) & 1;
        int tsrc = dq ? (31 - s0) : s0;
        float sgn = (dq && f >= 64) ? -1.f : 1.f;
        astf(XinA + dq * 131072 + s0 * 8192 + (f >> 1) * 128 + b * 2 + (f & 1),
             x[((size_t)b * 32 + tsrc) * FD + f] * sgn);
        if (q < 64 * 128) {
            int bb = q >> 7, ff = q & 127;
            out[((size_t)bb * TOTAL + 0) * FD + ff]   = x[((size_t)bb * 32 + 0) * FD + ff];
            out[((size_t)bb * TOTAL + 255) * FD + ff] = x[((size_t)bb * 32 + 31) * FD + ff];
        }
    }

    // ---------- stage weights to LDS (once; invalidation-immune)
    for (int d = tid; d < 8 * 512; d += THREADS) {
        int rl = d >> 9, k = d & 511;
        int rg = (rl >> 1) * 512 + wid * 2 + (rl & 1);
        wM[d]    = Mg[(size_t)rg * 512 + k];
        wWhh0[d] = Whh0[(size_t)rg * 512 + k];
    }
    for (int d = tid; d < 8 * 128; d += THREADS) {
        int rl = d >> 7, k = d & 127;
        int rg = (rl >> 1) * 512 + wid * 2 + (rl & 1);
        wWih0[d] = Wih0[(size_t)rg * 128 + k];
    }
    for (int d = tid; d < 8 * 1024; d += THREADS) {
        int rl = d >> 10, k = d & 1023;
        int rg = (rl >> 1) * 512 + wid * 2 + (rl & 1);
        wL1[d] = (k < 512) ? Wih1[(size_t)rg * 512 + k] : Whh1[(size_t)rg * 512 + (k - 512)];
    }
    for (int d = tid; d < 512; d += THREADS) wProj[d] = outW[(size_t)fC * 512 + d];
    for (int d = tid; d < 128; d += THREADS) outBl[d] = outB[d];
    __syncthreads();

    // ---------- persistent per-thread state (tid<128: u = tid>>6, b = tid&63)
    const int uE = tid >> 6, bE = tid & 63;
    float cc0_0 = 0.f, cc0_1 = 0.f, cc1_0 = 0.f, cc1_1 = 0.f;
    float GA0[4] = {0, 0, 0, 0}, GA1[4] = {0, 0, 0, 0};
    float acc2_0[8], acc2_1[8];
    float xreg = 0.f;
    float bA[4], bB[4], cvec[4];
    if (tid < 128) {
#pragma unroll
        for (int g = 0; g < 4; ++g) {
            int rg = g * 512 + wid * 2 + uE;
            bA[g] = bih0[rg] + bhh0[rg];
            bB[g] = bih1[rg] + bhh1[rg];
            int rl = g * 2 + uE;
            float cv = 0.f;
            for (int f = 0; f < 128; ++f) cv = fmaf(wWih0[rl * 128 + f], outBl[f], cv);
            cvec[g] = cv;
        }
    }
    const float outBias = outB[fC];
    const float sgC = (projDir && fC >= 64) ? -1.f : 1.f;

    // initial chip barrier (prologue visibility)
    bar_arrive(flags0, wid, 1u);
    bar_wait(flags0, 1u);

    // steps 0..253 full; step 254 = proj + final emission only (weight-0 tail dropped)
    for (int s = 0; s <= NSTEP - 1; ++s) {
        const bool last = (s == NSTEP - 1);
        float* h0w_0 = ws + WS_H0 + (s & 1) * 32768;
        const float* h0r_0 = ws + WS_H0 + ((s + 1) & 1) * 32768;
        float* h0w_1 = ws + WS_H0 + 65536 + (s & 1) * 32768;
        const float* h0r_1 = ws + WS_H0 + 65536 + ((s + 1) & 1) * 32768;
        float* h1w_0 = ws + WS_H1 + (s & 1) * 32768;
        const float* h1r_0 = ws + WS_H1 + ((s + 1) & 1) * 32768;
        float* h1w_1 = ws + WS_H1 + 65536 + (s & 1) * 32768;
        const float* h1r_1 = ws + WS_H1 + 65536 + ((s + 1) & 1) * 32768;

        A_REGION(0);
        if (s >= 1) bar_wait(flags1, 2u * s + 1u);   // prev-step B(d1)
        A_REGION(1);
        if (last) { EMIT(0); EMIT(1); break; }
        B_REGION(0);
        B_REGION(1);
        bar_wait(flags0, 2u * s + 3u);               // B(d0) before next A(d0)
    }
}

extern "C" void kernel_launch(void* const* d_in, const int* in_sizes, int n_in,
                              void* d_out, int out_size, void* d_ws, size_t ws_size,
                              hipStream_t stream) {
    const float* x    = (const float*)d_in[1];
    const float* Wih0 = (const float*)d_in[2];
    const float* Whh0 = (const float*)d_in[3];
    const float* bih0 = (const float*)d_in[4];
    const float* bhh0 = (const float*)d_in[5];
    const float* Wih1 = (const float*)d_in[6];
    const float* Whh1 = (const float*)d_in[7];
    const float* bih1 = (const float*)d_in[8];
    const float* bhh1 = (const float*)d_in[9];
    const float* outW = (const float*)d_in[10];
    const float* outB = (const float*)d_in[11];
    float* out = (float*)d_out;
    float* ws  = (float*)d_ws;

    (void)hipMemsetAsync(d_out, 0, (size_t)out_size * sizeof(float), stream);
    (void)hipMemsetAsync(d_ws, 0, (size_t)WS_ZERO * sizeof(float), stream);

    build_m_kernel<<<dim3(128), dim3(512), 0, stream>>>(Wih0, outW, ws);

    md_lstm_kernel<<<dim3(NWG), dim3(THREADS), 0, stream>>>(
        x, Wih0, Whh0, bih0, bhh0, Wih1, Whh1, bih1, bhh1, outW, outB, out, ws);
}

// Round 19
// 12337.247 us; speedup vs baseline: 3.4624x; 3.4624x over previous
//
#include <hip/hip_runtime.h>
#include <math.h>

#define FD 128
#define HD 512
#define TFS 16
#define NSTEP 255
#define TOTAL 256
#define NWG 256
#define THREADS 1024

// ws dword offsets
#define WS_FLAG 0      // chainA d0 @0, chainA d1 @256, chainB d0 @512, chainB d1 @768
#define WS_H0   1024                      // [dir][buf][256 kp][64 b][2] fp32 pair-k
#define WS_H1   (WS_H0 + 131072)
#define WS_XIN  (WS_H1 + 131072)          // [dir][16 s][64 kp][64 b][2] fp32 pair-k
#define WS_M    (WS_XIN + 262144)         // [2048 r][512 j] fused Wih0@outW
#define WS_END  (WS_M + 1048576)
#define WS_ZERO WS_XIN                    // zero flags + H0 + H1

__device__ __forceinline__ float sigm(float v) { return 1.0f / (1.0f + __expf(-v)); }

// LLC-coherent (agent-scope, relaxed) data plane — no bulk fences anywhere
__device__ __forceinline__ float aldf(const float* p) {
    return __hip_atomic_load(p, __ATOMIC_RELAXED, __HIP_MEMORY_SCOPE_AGENT);
}
__device__ __forceinline__ float2 aldf2(const float* p) {   // 8B coherent load
    unsigned long long v = __hip_atomic_load((const unsigned long long*)p,
                                             __ATOMIC_RELAXED, __HIP_MEMORY_SCOPE_AGENT);
    return __builtin_bit_cast(float2, v);
}
__device__ __forceinline__ void astf(float* p, float v) {
    __hip_atomic_store(p, v, __ATOMIC_RELAXED, __HIP_MEMORY_SCOPE_AGENT);
}
__device__ __forceinline__ unsigned aldu(const unsigned* p) {
    return __hip_atomic_load(p, __ATOMIC_RELAXED, __HIP_MEMORY_SCOPE_AGENT);
}

// arrival: all waves drain own coherent stores, barrier, one flag store (idx = 0..127)
__device__ __forceinline__ void bar_arrive(unsigned* flags, int idx, unsigned val) {
    asm volatile("s_waitcnt vmcnt(0)" ::: "memory");
    __syncthreads();
    if (threadIdx.x == 0) {
        __hip_atomic_store(flags + idx, val, __ATOMIC_RELAXED, __HIP_MEMORY_SCOPE_AGENT);
    }
}
// wait on 128 flags of own dir chain
__device__ __forceinline__ void bar_wait(const unsigned* flags, unsigned val) {
    if (threadIdx.x < 64) {
        const int l = threadIdx.x;
        for (;;) {
            unsigned m0 = aldu(flags + l);
            unsigned m1 = aldu(flags + l + 64);
            unsigned mn = m0 < m1 ? m0 : m1;
            if (__all(mn >= val)) break;
            __builtin_amdgcn_s_sleep(1);
        }
    }
    __syncthreads();
}
// initial barrier: wait on BOTH dirs' chainA
__device__ __forceinline__ void bar_wait_init(const unsigned* fA0, const unsigned* fA1) {
    if (threadIdx.x < 64) {
        const int l = threadIdx.x;
        for (;;) {
            unsigned m0 = aldu(fA0 + l), m1 = aldu(fA0 + l + 64);
            unsigned m2 = aldu(fA1 + l), m3 = aldu(fA1 + l + 64);
            unsigned a = m0 < m1 ? m0 : m1;
            unsigned b = m2 < m3 ? m2 : m3;
            unsigned mn = a < b ? a : b;
            if (__all(mn >= 1u)) break;
            __builtin_amdgcn_s_sleep(1);
        }
    }
    __syncthreads();
}

// acc[16] += W(16 rows x NCH*8 k, LDS broadcast) @ act(k x 64 cols, lane = col)
// pair-k act layout; act = base + (kbase>>1)*128 + 2*lane; chunk stride 512 floats.
template<int NCH>
__device__ __forceinline__ void gemv16(const float* __restrict__ act,
                                       const float* __restrict__ w1, int s1,
                                       float* __restrict__ acc)
{
    float2 ab[2][4];
#pragma unroll
    for (int p = 0; p < 4; ++p) ab[0][p] = aldf2(act + p * 128);
#pragma unroll
    for (int c = 0; c < NCH; ++c) {
        if (c + 1 < NCH) {
            const float* an = act + (c + 1) * 512;
#pragma unroll
            for (int p = 0; p < 4; ++p) ab[(c + 1) & 1][p] = aldf2(an + p * 128);
        }
        const float2* cb = ab[c & 1];
#pragma unroll
        for (int r = 0; r < 16; ++r) {
            const float* wr = w1 + r * s1 + c * 8;
            const float4 u0 = *(const float4*)wr;
            const float4 u1 = *(const float4*)(wr + 4);
            acc[r] = fmaf(u0.x, cb[0].x, acc[r]); acc[r] = fmaf(u0.y, cb[0].y, acc[r]);
            acc[r] = fmaf(u0.z, cb[1].x, acc[r]); acc[r] = fmaf(u0.w, cb[1].y, acc[r]);
            acc[r] = fmaf(u1.x, cb[2].x, acc[r]); acc[r] = fmaf(u1.y, cb[2].y, acc[r]);
            acc[r] = fmaf(u1.w, cb[3].y, fmaf(u1.z, cb[3].x, acc[r]));
        }
    }
}

// M = Wih0 [2048x128] @ outW [128x512]
__global__ __launch_bounds__(512)
void build_m_kernel(const float* __restrict__ Wih0, const float* __restrict__ outW,
                    float* __restrict__ ws)
{
    __shared__ float wl[16 * 128];
    const int tid = threadIdx.x;
    const int rb = (int)blockIdx.x;
    for (int d = tid; d < 16 * 128; d += 512)
        wl[d] = Wih0[(size_t)(rb * 16 + (d >> 7)) * 128 + (d & 127)];
    __syncthreads();
    const int j = tid;
    float acc[16];
#pragma unroll
    for (int r = 0; r < 16; ++r) acc[r] = 0.f;
    for (int f = 0; f < 128; ++f) {
        const float ov = outW[(size_t)f * 512 + j];
#pragma unroll
        for (int r = 0; r < 16; ++r) acc[r] = fmaf(wl[r * 128 + f], ov, acc[r]);
    }
    float* M = ws + WS_M;
#pragma unroll
    for (int r = 0; r < 16; ++r) M[(size_t)(rb * 16 + r) * 512 + j] = acc[r];
}

__global__ __launch_bounds__(THREADS)
void md_lstm_kernel(const float* __restrict__ x,
                    const float* __restrict__ Wih0, const float* __restrict__ Whh0,
                    const float* __restrict__ bih0, const float* __restrict__ bhh0,
                    const float* __restrict__ Wih1, const float* __restrict__ Whh1,
                    const float* __restrict__ bih1, const float* __restrict__ bhh1,
                    const float* __restrict__ outW, const float* __restrict__ outB,
                    float* __restrict__ out, float* __restrict__ ws)
{
    __shared__ __align__(16) float uA[16 * 512];     // 32 KB union: Wih0 (TF) / M (AR)
    __shared__ __align__(16) float wWhh0[16 * 512];  // 32 KB
    __shared__ __align__(16) float wL1[16 * 1024];   // 64 KB [Wih1 | Whh1]
    __shared__ __align__(16) float pLDS[4 * 16 * 64];// 16 KB fold buffers
    __shared__ __align__(16) float GAlds[16 * 64];   //  4 KB x-path gate accumulator
    __shared__ __align__(16) float projP[16 * 64];   //  4 KB
    __shared__ __align__(16) float wProj[512];       //  2 KB
    __shared__ float cvecl[16];
    __shared__ float outBl[128];

    const int tid = threadIdx.x;
    const int bid = (int)blockIdx.x;
    const int D = bid >> 7;               // direction owned by this wg
    const int U = bid & 127;              // unit group: units 4U..4U+3, fC = U
    const int wv = tid >> 6, l = tid & 63;

    unsigned* flagsA0 = (unsigned*)ws + WS_FLAG;
    unsigned* flagsA1 = flagsA0 + 256;
    unsigned* flagsA  = D ? flagsA1 : flagsA0;
    unsigned* flagsB  = (unsigned*)ws + WS_FLAG + 512 + D * 256;
    float* XinD = ws + WS_XIN + D * 131072;
    float* H0d  = ws + WS_H0 + D * 65536;
    float* H1d  = ws + WS_H1 + D * 65536;
    const float* Mg = ws + WS_M;

    // ---------- prologue: transposed signed Xin (pair-k, both dirs spread) + endpoints
    {
        int q = bid * THREADS + tid;      // 262144
        int b = q & 63, f = (q >> 6) & 127, s0 = (q >> 13) & 15, dq = (q >> 17) & 1;
        int tsrc = dq ? (31 - s0) : s0;
        float sgn = (dq && f >= 64) ? -1.f : 1.f;
        astf(ws + WS_XIN + dq * 131072 + s0 * 8192 + (f >> 1) * 128 + b * 2 + (f & 1),
             x[((size_t)b * 32 + tsrc) * FD + f] * sgn);
        if (q < 64 * 128) {
            int bb = q >> 7, ff = q & 127;
            out[((size_t)bb * TOTAL + 0) * FD + ff]   = x[((size_t)bb * 32 + 0) * FD + ff];
            out[((size_t)bb * TOTAL + 255) * FD + ff] = x[((size_t)bb * 32 + 31) * FD + ff];
        }
    }

    // ---------- stage weights to LDS (row rl = g*4+u -> global row g*512 + U*4 + u)
    for (int d = tid; d < 16 * 128; d += THREADS) {
        int rl = d >> 7, k = d & 127;
        int rg = (rl >> 2) * 512 + U * 4 + (rl & 3);
        uA[rl * 512 + k] = Wih0[(size_t)rg * 128 + k];
    }
    for (int d = tid; d < 16 * 512; d += THREADS) {
        int rl = d >> 9, k = d & 511;
        int rg = (rl >> 2) * 512 + U * 4 + (rl & 3);
        wWhh0[d] = Whh0[(size_t)rg * 512 + k];
    }
    for (int d = tid; d < 16 * 1024; d += THREADS) {
        int rl = d >> 10, k = d & 1023;
        int rg = (rl >> 2) * 512 + U * 4 + (rl & 3);
        wL1[d] = (k < 512) ? Wih1[(size_t)rg * 512 + k] : Whh1[(size_t)rg * 512 + (k - 512)];
    }
    for (int d = tid; d < 512; d += THREADS) wProj[d] = outW[(size_t)U * 512 + d];
    for (int d = tid; d < 128; d += THREADS) outBl[d] = outB[d];
    __syncthreads();
    if (tid < 16) {   // cvec from Wih0 (before AR overlay)
        float cv = 0.f;
        for (int f = 0; f < 128; ++f) cv = fmaf(uA[tid * 512 + f], outBl[f], cv);
        cvecl[tid] = cv;
    }

    // ---------- persistent per-thread state
    const int uE = tid >> 6, bE = tid & 63;     // cell threads (tid<256)
    float cc0 = 0.f, cc1 = 0.f, xreg = 0.f;
    float bA[4], bB[4];
    if (tid < 256) {
#pragma unroll
        for (int g = 0; g < 4; ++g) {
            int rg = g * 512 + U * 4 + uE;
            bA[g] = bih0[rg] + bhh0[rg];
            bB[g] = bih1[rg] + bhh1[rg];
        }
    }
    const float outBias = outB[U];
    const float sgC = (D && U >= 64) ? -1.f : 1.f;

    // initial global barrier (prologue visibility, both dirs)
    bar_arrive(flagsA, U, 1u);
    bar_wait_init(flagsA0, flagsA1);

    for (int s = 0; s <= NSTEP - 1; ++s) {
        const bool last = (s == NSTEP - 1);
        float* h0w = H0d + (s & 1) * 32768;
        const float* h0r = H0d + ((s + 1) & 1) * 32768;
        float* h1w = H1d + (s & 1) * 32768;
        const float* h1r = H1d + ((s + 1) & 1) * 32768;

        // ---- A h-path (Whh0·h0[s-1]) BEFORE the chainB wait (independent of h1)
        float accH[16];
        if (!last && wv >= 8) {
#pragma unroll
            for (int r = 0; r < 16; ++r) accH[r] = 0.f;
            gemv16<8>(h0r + (wv - 8) * 4096 + 2 * l, wWhh0 + 64 * (wv - 8), 512, accH);
        }
        if (s >= 1) bar_wait(flagsB, (unsigned)s);   // h1[s-1] + x ready chip-wide

        if (s == TFS) {   // overlay: replace Wih0 with M in uA (one-time)
            for (int d = tid; d < 16 * 512; d += THREADS) {
                int rl = d >> 9, k = d & 511;
                int rg = (rl >> 2) * 512 + U * 4 + (rl & 3);
                uA[d] = Mg[(size_t)rg * 512 + k];
            }
            __syncthreads();
        }

        if (last) {   // final emission only (uses h1[253])
            {
                const float* hp = h1r + wv * 2048 + 2 * l;
                float p = 0.f;
#pragma unroll
                for (int kp = 0; kp < 16; ++kp) {
                    float2 hv = aldf2(hp + kp * 128);
                    p = fmaf(wProj[wv * 32 + 2 * kp], hv.x, p);
                    p = fmaf(wProj[wv * 32 + 2 * kp + 1], hv.y, p);
                }
                projP[wv * 64 + l] = p;
            }
            __syncthreads();
            if (tid < 64) {
                float P = outBias;
#pragma unroll
                for (int w2 = 0; w2 < 16; ++w2) P += projP[w2 * 64 + tid];
                float xn = xreg + P;
                int oidx = D ? (255 - s) : s;
                float wgt = (float)(255 - s) * (1.0f / 255.0f);
                atomicAdd(out + ((size_t)tid * TOTAL + oidx) * FD + U, wgt * xn * sgC);
            }
            break;
        }

        // ---- A x-path: TF Wih0·x, AR M·h1[s-1]
        float accX[16];
        if (wv < 8) {
#pragma unroll
            for (int r = 0; r < 16; ++r) accX[r] = 0.f;
            if (s < TFS) gemv16<2>(XinD + s * 8192 + wv * 1024 + 2 * l, uA + 16 * wv, 512, accX);
            else         gemv16<8>(h1r + wv * 4096 + 2 * l, uA + 64 * wv, 512, accX);
        }
        // fold A stage 1 (x-path, waves 0-7)
        if (wv < 4) {
#pragma unroll
            for (int r = 0; r < 16; ++r) pLDS[wv * 1024 + r * 64 + l] = accX[r];
        }
        __syncthreads();
        if (wv >= 4 && wv < 8) {
#pragma unroll
            for (int r = 0; r < 16; ++r) pLDS[(wv - 4) * 1024 + r * 64 + l] += accX[r];
        }
        __syncthreads();
        {   // GA update (1024 threads: rl = tid>>6, b = tid&63)
            int idx = (tid >> 6) * 64 + (tid & 63);
            float xs = pLDS[idx] + pLDS[1024 + idx] + pLDS[2048 + idx] + pLDS[3072 + idx];
            if (s < TFS) GAlds[idx] = xs;
            else         GAlds[idx] += xs + cvecl[tid >> 6];
        }
        __syncthreads();
        // fold A stage 2 (h-path, waves 8-15)
        if (wv >= 8 && wv < 12) {
#pragma unroll
            for (int r = 0; r < 16; ++r) pLDS[(wv - 8) * 1024 + r * 64 + l] = accH[r];
        }
        __syncthreads();
        if (wv >= 12) {
#pragma unroll
            for (int r = 0; r < 16; ++r) pLDS[(wv - 12) * 1024 + r * 64 + l] += accH[r];
        }
        __syncthreads();
        if (tid < 256) {   // layer-0 cell update -> h0w
            float gv[4];
#pragma unroll
            for (int g = 0; g < 4; ++g) {
                int idx = (g * 4 + uE) * 64 + bE;
                float fh = pLDS[idx] + pLDS[1024 + idx] + pLDS[2048 + idx] + pLDS[3072 + idx];
                gv[g] = GAlds[idx] + fh + bA[g];
            }
            float cn = sigm(gv[1]) * cc0 + sigm(gv[0]) * tanhf(gv[2]);
            cc0 = cn;
            astf(h0w + (U * 2 + (uE >> 1)) * 128 + bE * 2 + (uE & 1), sigm(gv[3]) * tanhf(cn));
        }
        bar_arrive(flagsA, U, (unsigned)(s + 2));

        // ---- proj partials (h1[s-1]) + B h1-path (Whh1·h1[s-1]) hide the chainA wait
        {
            const float* hp = h1r + wv * 2048 + 2 * l;
            float p = 0.f;
#pragma unroll
            for (int kp = 0; kp < 16; ++kp) {
                float2 hv = aldf2(hp + kp * 128);
                p = fmaf(wProj[wv * 32 + 2 * kp], hv.x, p);
                p = fmaf(wProj[wv * 32 + 2 * kp + 1], hv.y, p);
            }
            projP[wv * 64 + l] = p;
        }
        float accB[16];
        if (wv >= 8) {
#pragma unroll
            for (int r = 0; r < 16; ++r) accB[r] = 0.f;
            gemv16<8>(h1r + (wv - 8) * 4096 + 2 * l, wL1 + 512 + 64 * (wv - 8), 1024, accB);
        }
        bar_wait(flagsA, (unsigned)(s + 2));   // h0w ready chip-wide

        if (s >= 1 && tid < 64) {   // EMIT position s
            float P = outBias;
#pragma unroll
            for (int w2 = 0; w2 < 16; ++w2) P += projP[w2 * 64 + tid];
            float xprev = (s - 1 < TFS)
                ? aldf(XinD + (s - 1) * 8192 + (U >> 1) * 128 + tid * 2 + (U & 1))
                : xreg;
            float xn = xprev + P;
            xreg = xn;
            int oidx = D ? (255 - s) : s;
            float wgt = (float)(255 - s) * (1.0f / 255.0f);
            atomicAdd(out + ((size_t)tid * TOTAL + oidx) * FD + U, wgt * xn * sgC);
        }

        // ---- B h0-path (Wih1·h0w)
        if (wv < 8) {
#pragma unroll
            for (int r = 0; r < 16; ++r) accB[r] = 0.f;
            gemv16<8>(h0w + wv * 4096 + 2 * l, wL1 + 64 * wv, 1024, accB);
        }
        // fold B: single 4-stage tree
        if (wv < 4) {
#pragma unroll
            for (int r = 0; r < 16; ++r) pLDS[wv * 1024 + r * 64 + l] = accB[r];
        }
        __syncthreads();
        if (wv >= 4 && wv < 8) {
#pragma unroll
            for (int r = 0; r < 16; ++r) pLDS[(wv - 4) * 1024 + r * 64 + l] += accB[r];
        }
        __syncthreads();
        if (wv >= 8 && wv < 12) {
#pragma unroll
            for (int r = 0; r < 16; ++r) pLDS[(wv - 8) * 1024 + r * 64 + l] += accB[r];
        }
        __syncthreads();
        if (wv >= 12) {
#pragma unroll
            for (int r = 0; r < 16; ++r) pLDS[(wv - 12) * 1024 + r * 64 + l] += accB[r];
        }
        __syncthreads();
        if (tid < 256) {   // layer-1 cell update -> h1w
            float gv[4];
#pragma unroll
            for (int g = 0; g < 4; ++g) {
                int idx = (g * 4 + uE) * 64 + bE;
                gv[g] = pLDS[idx] + pLDS[1024 + idx] + pLDS[2048 + idx] + pLDS[3072 + idx] + bB[g];
            }
            float cn = sigm(gv[1]) * cc1 + sigm(gv[0]) * tanhf(gv[2]);
            cc1 = cn;
            astf(h1w + (U * 2 + (uE >> 1)) * 128 + bE * 2 + (uE & 1), sigm(gv[3]) * tanhf(cn));
        }
        bar_arrive(flagsB, U, (unsigned)(s + 1));
    }
}

extern "C" void kernel_launch(void* const* d_in, const int* in_sizes, int n_in,
                              void* d_out, int out_size, void* d_ws, size_t ws_size,
                              hipStream_t stream) {
    const float* x    = (const float*)d_in[1];
    const float* Wih0 = (const float*)d_in[2];
    const float* Whh0 = (const float*)d_in[3];
    const float* bih0 = (const float*)d_in[4];
    const float* bhh0 = (const float*)d_in[5];
    const float* Wih1 = (const float*)d_in[6];
    const float* Whh1 = (const float*)d_in[7];
    const float* bih1 = (const float*)d_in[8];
    const float* bhh1 = (const float*)d_in[9];
    const float* outW = (const float*)d_in[10];
    const float* outB = (const float*)d_in[11];
    float* out = (float*)d_out;
    float* ws  = (float*)d_ws;

    (void)hipMemsetAsync(d_out, 0, (size_t)out_size * sizeof(float), stream);
    (void)hipMemsetAsync(d_ws, 0, (size_t)WS_ZERO * sizeof(float), stream);

    build_m_kernel<<<dim3(128), dim3(512), 0, stream>>>(Wih0, outW, ws);

    md_lstm_kernel<<<dim3(NWG), dim3(THREADS), 0, stream>>>(
        x, Wih0, Whh0, bih0, bhh0, Wih1, Whh1, bih1, bhh1, outW, outB, out, ws);
}

// Round 20
// 9297.793 us; speedup vs baseline: 4.5943x; 1.3269x over previous
//
#include <hip/hip_runtime.h>
#include <math.h>

#define FD 128
#define HD 512
#define TFS 16
#define NSTEP 255
#define TOTAL 256
#define NWG 256
#define THREADS 1024

// ws dword offsets
#define WS_FLAG 0                         // 2 chains x 256 flags (padded to 512 each)
#define WS_H0   1024                      // [dir][buf][256 kp][64 b][2] fp32 pair-k
#define WS_H1   (WS_H0 + 131072)
#define WS_XIN  (WS_H1 + 131072)          // [dir][16 s][64 fp][64 b][2] fp32 pair-k
#define WS_M    (WS_XIN + 262144)         // [2048 r][512 j] fused Wih0@outW
#define WS_END  (WS_M + 1048576)
#define WS_ZERO WS_XIN                    // zero flags + H0 + H1

__device__ __forceinline__ float sigm(float v) { return 1.0f / (1.0f + __expf(-v)); }

// LLC-coherent (agent-scope, relaxed) data plane — no bulk fences needed
__device__ __forceinline__ float aldf(const float* p) {
    return __hip_atomic_load(p, __ATOMIC_RELAXED, __HIP_MEMORY_SCOPE_AGENT);
}
__device__ __forceinline__ float2 aldf2(const float* p) {   // 8B atomic load (aligned)
    unsigned long long v = __hip_atomic_load((const unsigned long long*)p,
                                             __ATOMIC_RELAXED, __HIP_MEMORY_SCOPE_AGENT);
    return __builtin_bit_cast(float2, v);
}
__device__ __forceinline__ void astf(float* p, float v) {
    __hip_atomic_store(p, v, __ATOMIC_RELAXED, __HIP_MEMORY_SCOPE_AGENT);
}
__device__ __forceinline__ unsigned aldu(const unsigned* p) {
    return __hip_atomic_load(p, __ATOMIC_RELAXED, __HIP_MEMORY_SCOPE_AGENT);
}

// arrival: every wave drains its own coherent stores, then barrier, then flag store
__device__ __forceinline__ void bar_arrive(unsigned* flags, int wid, unsigned val) {
    asm volatile("s_waitcnt vmcnt(0)" ::: "memory");
    __syncthreads();
    if (threadIdx.x == 0) {
        __hip_atomic_store(flags + wid, val, __ATOMIC_RELAXED, __HIP_MEMORY_SCOPE_AGENT);
    }
}
// wait: wave0 polls all 256 flags (coalesced LLC loads)
__device__ __forceinline__ void bar_wait(const unsigned* flags, unsigned val) {
    if (threadIdx.x < 64) {
        const int l = threadIdx.x;
        for (;;) {
            unsigned m0 = aldu(flags + l);
            unsigned m1 = aldu(flags + l + 64);
            unsigned m2 = aldu(flags + l + 128);
            unsigned m3 = aldu(flags + l + 192);
            unsigned a = m0 < m1 ? m0 : m1;
            unsigned b = m2 < m3 ? m2 : m3;
            unsigned mn = a < b ? a : b;
            if (__all(mn >= val)) break;
            __builtin_amdgcn_s_sleep(1);
        }
    }
    __syncthreads();
}

// a1[8] (+ a2[8] if DUAL) += W(8 rows x NCH*8 k, LDS broadcast) @ act(k x 64, lane=col)
// Pair-k act layout: element (k,b) at (k>>1)*128 + 2b + (k&1); caller passes
// act = base + (kbase>>1)*128 + 2*lane. Chunk stride = 512 floats (unchanged).
// 8B atomic loads halve instruction count and double bytes-in-flight.
template<int NCH, bool DUAL>
__device__ __forceinline__ void gemv8(const float* __restrict__ act,
                                      const float* __restrict__ w1, int s1,
                                      const float* __restrict__ w2, int s2,
                                      float* __restrict__ a1, float* __restrict__ a2)
{
    float2 ab[2][4];
#pragma unroll
    for (int p = 0; p < 4; ++p) ab[0][p] = aldf2(act + p * 128);
#pragma unroll
    for (int c = 0; c < NCH; ++c) {
        if (c + 1 < NCH) {
            const float* an = act + (c + 1) * 512;
#pragma unroll
            for (int p = 0; p < 4; ++p) ab[(c + 1) & 1][p] = aldf2(an + p * 128);
        }
        const float2* cb = ab[c & 1];
#pragma unroll
        for (int r = 0; r < 8; ++r) {
            const float* wr = w1 + r * s1 + c * 8;
            const float4 u0 = *(const float4*)wr;
            const float4 u1 = *(const float4*)(wr + 4);
            a1[r] = fmaf(u0.x, cb[0].x, a1[r]); a1[r] = fmaf(u0.y, cb[0].y, a1[r]);
            a1[r] = fmaf(u0.z, cb[1].x, a1[r]); a1[r] = fmaf(u0.w, cb[1].y, a1[r]);
            a1[r] = fmaf(u1.x, cb[2].x, a1[r]); a1[r] = fmaf(u1.y, cb[2].y, a1[r]);
            a1[r] = fmaf(u1.w, cb[3].y, fmaf(u1.z, cb[3].x, a1[r]));
        }
        if (DUAL) {
#pragma unroll
            for (int r = 0; r < 8; ++r) {
                const float* wr = w2 + r * s2 + c * 8;
                const float4 u0 = *(const float4*)wr;
                const float4 u1 = *(const float4*)(wr + 4);
                a2[r] = fmaf(u0.x, cb[0].x, a2[r]); a2[r] = fmaf(u0.y, cb[0].y, a2[r]);
                a2[r] = fmaf(u0.z, cb[1].x, a2[r]); a2[r] = fmaf(u0.w, cb[1].y, a2[r]);
                a2[r] = fmaf(u1.x, cb[2].x, a2[r]); a2[r] = fmaf(u1.y, cb[2].y, a2[r]);
                a2[r] = fmaf(u1.w, cb[3].y, fmaf(u1.z, cb[3].x, a2[r]));
            }
        }
    }
}

// M = Wih0 [2048x128] @ outW [128x512]
__global__ __launch_bounds__(512)
void build_m_kernel(const float* __restrict__ Wih0, const float* __restrict__ outW,
                    float* __restrict__ ws)
{
    __shared__ float wl[16 * 128];
    const int tid = threadIdx.x;
    const int rb = (int)blockIdx.x;
    for (int d = tid; d < 16 * 128; d += 512)
        wl[d] = Wih0[(size_t)(rb * 16 + (d >> 7)) * 128 + (d & 127)];
    __syncthreads();
    const int j = tid;
    float acc[16];
#pragma unroll
    for (int r = 0; r < 16; ++r) acc[r] = 0.f;
    for (int f = 0; f < 128; ++f) {
        const float ov = outW[(size_t)f * 512 + j];
#pragma unroll
        for (int r = 0; r < 16; ++r) acc[r] = fmaf(wl[r * 128 + f], ov, acc[r]);
    }
    float* M = ws + WS_M;
#pragma unroll
    for (int r = 0; r < 16; ++r) M[(size_t)(rb * 16 + r) * 512 + j] = acc[r];
}

// output emission for step s, dir D (weight-0 terms at s=255 dropped by loop bound)
#define EMIT(D) do {                                                                 \
    if (projDir == D && tid < 64) {                                                  \
        float P = outBias;                                                           \
        _Pragma("unroll") for (int w2 = 0; w2 < 16; ++w2) P += projP[w2 * 64 + tid]; \
        float xprev = (s - 1 < TFS)                                                  \
            ? aldf(XinA + (D)*131072 + (s - 1) * 8192 + (fC >> 1) * 128 + tid * 2 + (fC & 1)) \
            : xreg;                                                                  \
        float xn = xprev + P;                                                        \
        xreg = xn;                                                                   \
        int oidx = (D) ? (255 - s) : s;                                              \
        float wgt = (float)(255 - s) * (1.0f / 255.0f);                              \
        atomicAdd(out + ((size_t)tid * TOTAL + oidx) * FD + fC, wgt * xn * sgC);     \
    }                                                                                \
} while (0)

#define A_REGION(D) do {                                                               \
    if (s >= 1 && projDir == D) {                                                      \
        const float* hp = h1r_##D + (wv * 32) * 64 + 2 * l;                            \
        float p = 0.f;                                                                 \
        _Pragma("unroll")                                                              \
        for (int kp = 0; kp < 16; ++kp) {                                              \
            float2 hv = aldf2(hp + kp * 128);                                          \
            p = fmaf(wProj[wv * 32 + 2 * kp], hv.x, p);                                \
            p = fmaf(wProj[wv * 32 + 2 * kp + 1], hv.y, p);                            \
        }                                                                              \
        projP[wv * 64 + l] = p;                                                        \
    }                                                                                  \
    if (!last) {                                                                       \
        float a1[8];                                                                   \
        _Pragma("unroll") for (int r = 0; r < 8; ++r) a1[r] = 0.f;                     \
        if (s < TFS) {                                                                 \
            if (wv < 8) gemv8<2, false>(XinA + (D)*131072 + s * 8192 + (wv * 16) * 64 + 2 * l, \
                                        wWih0 + wv * 16, 128, wWih0, 0, a1, a1);       \
            else        gemv8<8, false>(h0r_##D + ((wv - 8) * 64) * 64 + 2 * l,        \
                                        wWhh0 + (wv - 8) * 64, 512, wWhh0, 0, a1, a1); \
        } else {                                                                       \
            if (wv < 8) {                                                              \
                _Pragma("unroll") for (int r = 0; r < 8; ++r) acc2_##D[r] = 0.f;       \
                gemv8<8, true>(h1r_##D + (wv * 64) * 64 + 2 * l, wM + wv * 64, 512,    \
                               wL1 + 512 + wv * 64, 1024, a1, acc2_##D);               \
            } else                                                                     \
                gemv8<8, false>(h0r_##D + ((wv - 8) * 64) * 64 + 2 * l,                \
                                wWhh0 + (wv - 8) * 64, 512, wWhh0, 0, a1, a1);         \
        }                                                                              \
        _Pragma("unroll") for (int r = 0; r < 8; ++r) pLDS[wv * 512 + r * 64 + l] = a1[r]; \
    }                                                                                  \
    __syncthreads();                                                                   \
    if (!last) {                                                                       \
        if (tid < 128) {                                                               \
            float g[4];                                                                 \
            _Pragma("unroll") for (int gg = 0; gg < 4; ++gg) {                         \
                int rl = gg * 2 + uE;                                                  \
                float ft = 0.f, fh = 0.f;                                              \
                _Pragma("unroll") for (int w2 = 0; w2 < 8; ++w2)  ft += pLDS[w2 * 512 + rl * 64 + bE]; \
                _Pragma("unroll") for (int w2 = 8; w2 < 16; ++w2) fh += pLDS[w2 * 512 + rl * 64 + bE]; \
                if (s < TFS) GA##D[gg] = ft;                                           \
                else         GA##D[gg] += ft + cvec[gg];                               \
                g[gg] = GA##D[gg] + fh + bA[gg];                                       \
            }                                                                          \
            float cn = sigm(g[1]) * cc0_##D + sigm(g[0]) * tanhf(g[2]);                \
            cc0_##D = cn;                                                              \
            astf(h0w_##D + wid * 128 + bE * 2 + uE, sigm(g[3]) * tanhf(cn));           \
        }                                                                              \
        bar_arrive(flags##D, wid, 2u * s + 2u);                                        \
    }                                                                                  \
} while (0)

#define B_REGION(D) do {                                                               \
    bar_wait(flags##D, 2u * s + 2u);                                                   \
    if (s >= 1) EMIT(D);                                                               \
    {                                                                                  \
        float a1[8];                                                                   \
        _Pragma("unroll") for (int r = 0; r < 8; ++r) a1[r] = 0.f;                     \
        if (s < TFS) {                                                                 \
            if (wv < 8) gemv8<8, false>(h0w_##D + (wv * 64) * 64 + 2 * l,              \
                                        wL1 + wv * 64, 1024, wL1, 0, a1, a1);          \
            else        gemv8<8, false>(h1r_##D + ((wv - 8) * 64) * 64 + 2 * l,        \
                                        wL1 + 512 + (wv - 8) * 64, 1024, wL1, 0, a1, a1); \
        } else {                                                                       \
            gemv8<4, false>(h0w_##D + (wv * 32) * 64 + 2 * l, wL1 + wv * 32, 1024, wL1, 0, a1, a1); \
            if (wv < 8) { _Pragma("unroll") for (int r = 0; r < 8; ++r) a1[r] += acc2_##D[r]; } \
        }                                                                              \
        _Pragma("unroll") for (int r = 0; r < 8; ++r) pLDS[wv * 512 + r * 64 + l] = a1[r]; \
    }                                                                                  \
    __syncthreads();                                                                   \
    if (tid < 128) {                                                                   \
        float g[4];                                                                     \
        _Pragma("unroll") for (int gg = 0; gg < 4; ++gg) {                             \
            int rl = gg * 2 + uE;                                                      \
            float fs = 0.f;                                                            \
            _Pragma("unroll") for (int w2 = 0; w2 < 16; ++w2) fs += pLDS[w2 * 512 + rl * 64 + bE]; \
            g[gg] = fs + bB[gg];                                                       \
        }                                                                              \
        float cn = sigm(g[1]) * cc1_##D + sigm(g[0]) * tanhf(g[2]);                    \
        cc1_##D = cn;                                                                  \
        astf(h1w_##D + wid * 128 + bE * 2 + uE, sigm(g[3]) * tanhf(cn));               \
    }                                                                                  \
    bar_arrive(flags##D, wid, 2u * s + 3u);                                            \
} while (0)

__global__ __launch_bounds__(THREADS)
void md_lstm_kernel(const float* __restrict__ x,
                    const float* __restrict__ Wih0, const float* __restrict__ Whh0,
                    const float* __restrict__ bih0, const float* __restrict__ bhh0,
                    const float* __restrict__ Wih1, const float* __restrict__ Whh1,
                    const float* __restrict__ bih1, const float* __restrict__ bhh1,
                    const float* __restrict__ outW, const float* __restrict__ outB,
                    float* __restrict__ out, float* __restrict__ ws)
{
    __shared__ __align__(16) float wWih0[8 * 128];   //  4 KB
    __shared__ __align__(16) float wWhh0[8 * 512];   // 16 KB
    __shared__ __align__(16) float wM[8 * 512];      // 16 KB
    __shared__ __align__(16) float wL1[8 * 1024];    // 32 KB [Wih1|Whh1]
    __shared__ __align__(16) float wProj[512];       //  2 KB
    __shared__ __align__(16) float pLDS[16 * 512];   // 32 KB [wave][8 rl][64 b]
    __shared__ __align__(16) float projP[16 * 64];   //  4 KB
    __shared__ float outBl[128];

    const int tid = threadIdx.x;
    const int bid = (int)blockIdx.x;
    const int wid = bid;                  // wg owns units {2wid, 2wid+1} in both layers/dirs
    const int wv = tid >> 6, l = tid & 63;
    const int projDir = wid & 1;
    const int fC = wid >> 1;

    unsigned* flags0 = (unsigned*)ws + WS_FLAG;
    unsigned* flags1 = flags0 + 512;
    float* XinA = ws + WS_XIN;
    const float* Mg = ws + WS_M;

    // ---------- prologue: transposed signed Xin per dir (pair-k layout) + endpoints
    {
        int q = bid * THREADS + tid;      // exactly 2*16*128*64 = 262144
        int b = q & 63, f = (q >> 6) & 127, s0 = (q >> 13) & 15, dq = (q >> 17) & 1;
        int tsrc = dq ? (31 - s0) : s0;
        float sgn = (dq && f >= 64) ? -1.f : 1.f;
        astf(XinA + dq * 131072 + s0 * 8192 + (f >> 1) * 128 + b * 2 + (f & 1),
             x[((size_t)b * 32 + tsrc) * FD + f] * sgn);
        if (q < 64 * 128) {
            int bb = q >> 7, ff = q & 127;
            out[((size_t)bb * TOTAL + 0) * FD + ff]   = x[((size_t)bb * 32 + 0) * FD + ff];
            out[((size_t)bb * TOTAL + 255) * FD + ff] = x[((size_t)bb * 32 + 31) * FD + ff];
        }
    }

    // ---------- stage weights to LDS (once; invalidation-immune)
    for (int d = tid; d < 8 * 512; d += THREADS) {
        int rl = d >> 9, k = d & 511;
        int rg = (rl >> 1) * 512 + wid * 2 + (rl & 1);
        wM[d]    = Mg[(size_t)rg * 512 + k];
        wWhh0[d] = Whh0[(size_t)rg * 512 + k];
    }
    for (int d = tid; d < 8 * 128; d += THREADS) {
        int rl = d >> 7, k = d & 127;
        int rg = (rl >> 1) * 512 + wid * 2 + (rl & 1);
        wWih0[d] = Wih0[(size_t)rg * 128 + k];
    }
    for (int d = tid; d < 8 * 1024; d += THREADS) {
        int rl = d >> 10, k = d & 1023;
        int rg = (rl >> 1) * 512 + wid * 2 + (rl & 1);
        wL1[d] = (k < 512) ? Wih1[(size_t)rg * 512 + k] : Whh1[(size_t)rg * 512 + (k - 512)];
    }
    for (int d = tid; d < 512; d += THREADS) wProj[d] = outW[(size_t)fC * 512 + d];
    for (int d = tid; d < 128; d += THREADS) outBl[d] = outB[d];
    __syncthreads();

    // ---------- persistent per-thread state (tid<128: u = tid>>6, b = tid&63)
    const int uE = tid >> 6, bE = tid & 63;
    float cc0_0 = 0.f, cc0_1 = 0.f, cc1_0 = 0.f, cc1_1 = 0.f;
    float GA0[4] = {0, 0, 0, 0}, GA1[4] = {0, 0, 0, 0};
    float acc2_0[8], acc2_1[8];
    float xreg = 0.f;
    float bA[4], bB[4], cvec[4];
    if (tid < 128) {
#pragma unroll
        for (int g = 0; g < 4; ++g) {
            int rg = g * 512 + wid * 2 + uE;
            bA[g] = bih0[rg] + bhh0[rg];
            bB[g] = bih1[rg] + bhh1[rg];
            int rl = g * 2 + uE;
            float cv = 0.f;
            for (int f = 0; f < 128; ++f) cv = fmaf(wWih0[rl * 128 + f], outBl[f], cv);
            cvec[g] = cv;
        }
    }
    const float outBias = outB[fC];
    const float sgC = (projDir && fC >= 64) ? -1.f : 1.f;

    // initial chip barrier (prologue visibility)
    bar_arrive(flags0, wid, 1u);
    bar_wait(flags0, 1u);

    // steps 0..253 full; step 254 = proj + final emission only (weight-0 tail dropped)
    for (int s = 0; s <= NSTEP - 1; ++s) {
        const bool last = (s == NSTEP - 1);
        float* h0w_0 = ws + WS_H0 + (s & 1) * 32768;
        const float* h0r_0 = ws + WS_H0 + ((s + 1) & 1) * 32768;
        float* h0w_1 = ws + WS_H0 + 65536 + (s & 1) * 32768;
        const float* h0r_1 = ws + WS_H0 + 65536 + ((s + 1) & 1) * 32768;
        float* h1w_0 = ws + WS_H1 + (s & 1) * 32768;
        const float* h1r_0 = ws + WS_H1 + ((s + 1) & 1) * 32768;
        float* h1w_1 = ws + WS_H1 + 65536 + (s & 1) * 32768;
        const float* h1r_1 = ws + WS_H1 + 65536 + ((s + 1) & 1) * 32768;

        A_REGION(0);
        if (s >= 1) bar_wait(flags1, 2u * s + 1u);   // prev-step B(d1)
        A_REGION(1);
        if (last) { EMIT(0); EMIT(1); break; }
        B_REGION(0);
        B_REGION(1);
        bar_wait(flags0, 2u * s + 3u);               // B(d0) before next A(d0)
    }
}

extern "C" void kernel_launch(void* const* d_in, const int* in_sizes, int n_in,
                              void* d_out, int out_size, void* d_ws, size_t ws_size,
                              hipStream_t stream) {
    const float* x    = (const float*)d_in[1];
    const float* Wih0 = (const float*)d_in[2];
    const float* Whh0 = (const float*)d_in[3];
    const float* bih0 = (const float*)d_in[4];
    const float* bhh0 = (const float*)d_in[5];
    const float* Wih1 = (const float*)d_in[6];
    const float* Whh1 = (const float*)d_in[7];
    const float* bih1 = (const float*)d_in[8];
    const float* bhh1 = (const float*)d_in[9];
    const float* outW = (const float*)d_in[10];
    const float* outB = (const float*)d_in[11];
    float* out = (float*)d_out;
    float* ws  = (float*)d_ws;

    (void)hipMemsetAsync(d_out, 0, (size_t)out_size * sizeof(float), stream);
    (void)hipMemsetAsync(d_ws, 0, (size_t)WS_ZERO * sizeof(float), stream);

    build_m_kernel<<<dim3(128), dim3(512), 0, stream>>>(Wih0, outW, ws);

    md_lstm_kernel<<<dim3(NWG), dim3(THREADS), 0, stream>>>(
        x, Wih0, Whh0, bih0, bhh0, Wih1, Whh1, bih1, bhh1, outW, outB, out, ws);
}